// Round 11
// baseline (245.229 us; speedup 1.0000x reference)
//
#include <hip/hip_runtime.h>

// (B, DIM, HEADS, H, W, WS, AWS) = (8, 64, 4, 256, 256, 8, 8); HD=16, no padding, SCALE=0.25
#define BATCH 8
#define CDIM 64
#define NHEADS 4
#define HD 16
#define IMG 256
#define WSZ 8
#define WN 32
#define NWIN (WN * WN)

static constexpr size_t OFFSC_FLOATS = (size_t)BATCH * NHEADS * NWIN * 4;     // 131072
static constexpr size_t MAP_ELEMS = (size_t)BATCH * NHEADS * IMG * IMG * HD;  // 33,554,432 per map
static constexpr size_t BIAST_FLOATS = 4 * 4 * 4 * 64 * 4;                    // 16384 (64 KB)

typedef unsigned short u16;
typedef __attribute__((ext_vector_type(2))) _Float16 h2;
typedef __attribute__((ext_vector_type(8))) _Float16 h8;
typedef __attribute__((ext_vector_type(4))) float f32x4;

// ---------- helpers ----------
__device__ __forceinline__ unsigned cvt_pk_f16(float a, float b) {  // lo=h(a), hi=h(b), RTZ
    unsigned r;
    asm("v_cvt_pkrtz_f16_f32 %0, %1, %2" : "=v"(r) : "v"(a), "v"(b));
    return r;
}
__device__ __forceinline__ float rcpf(float s) {
    float r;
    asm("v_rcp_f32 %0, %1" : "=v"(r) : "v"(s));
    return r;
}
union UH2 { unsigned u; h2 h; };
__device__ __forceinline__ h2 u2h2(unsigned u) { UH2 x; x.u = u; return x.h; }
__device__ __forceinline__ unsigned h22u(h2 h) { UH2 x; x.h = h; return x.u; }
__device__ __forceinline__ u16 f2h(float f) {   // RNE
    _Float16 h = (_Float16)f;
    u16 r;
    __builtin_memcpy(&r, &h, 2);
    return r;
}
__device__ __forceinline__ unsigned pk_rne(float a, float b) {  // RNE packed
    return (unsigned)f2h(a) | ((unsigned)f2h(b) << 16);
}

// DPP rotate-add within 16-lane row (VALU-only, no LDS): x += rotated(x)
#define DPP_RADD(x, ctrl)                                                         \
    x += __int_as_float(__builtin_amdgcn_update_dpp(                              \
        0, __float_as_int(x), (ctrl), 0xF, 0xF, false))

// ---------- kernel 1a: pool -> leaky (+ blocks 0..31: weight conv; 32..47: biasT table) ----------
__global__ __launch_bounds__(256) void k_pool(const float* __restrict__ x,
                                              float* __restrict__ actg,
                                              const float* __restrict__ qkv_w,
                                              const float* __restrict__ proj_w,
                                              unsigned* __restrict__ wbf,
                                              const float* __restrict__ rel_bias,
                                              float* __restrict__ biasT) {
    __shared__ float red[8][8][33];   // [c][row][ww]
    int bid = blockIdx.x;
    int cg = bid & 7, wh = (bid >> 3) & 31, b = bid >> 8;
    int t = threadIdx.x;
    int row = t >> 5, colg = t & 31;

    if (bid < 32) {
        int i = bid * 256 + t;   // dword-pair index
        if (i < 6144) {
            wbf[i] = cvt_pk_f16(qkv_w[2 * i], qkv_w[2 * i + 1]);
        } else {
            int j = i - 6144;
            wbf[i] = cvt_pk_f16(proj_w[2 * j], proj_w[2 * j + 1]);
        }
    } else if (bid < 48) {
        // per-lane QK^T bias table: biasT[((n*4+qt)*4+kt)*64 + l] = float4 of acc-init biases
        int i = (bid - 32) * 256 + t;   // 0..4095
        int l = i & 63, kt = (i >> 6) & 3, qt = (i >> 8) & 3, n = i >> 10;
        int g = l >> 4, cl = l & 15;
        int pik = kt * 2 + (cl >> 3), pjk = cl & 7;
        int bidx = (7 - pik) * 15 + (7 - pjk) + (qt * 2 + (g >> 1)) * 15 + (g & 1) * 4;
        float4 v;
        v.x = rel_bias[(bidx + 0) * NHEADS + n] * 4.0f;
        v.y = rel_bias[(bidx + 1) * NHEADS + n] * 4.0f;
        v.z = rel_bias[(bidx + 2) * NHEADS + n] * 4.0f;
        v.w = rel_bias[(bidx + 3) * NHEADS + n] * 4.0f;
        ((float4*)biasT)[i] = v;
    }

    const float* xb = x + (((size_t)(b * CDIM + cg * 8) * IMG) + (size_t)(wh * WSZ + row)) * IMG + colg * 8;
    #pragma unroll
    for (int c = 0; c < 8; c++) {
        const float4* p4 = (const float4*)(xb + (size_t)c * IMG * IMG);
        float4 a = p4[0], bq = p4[1];
        red[c][row][colg] = a.x + a.y + a.z + a.w + bq.x + bq.y + bq.z + bq.w;
    }
    __syncthreads();
    int c = t >> 5, ww = t & 31;
    float s = 0.f;
    #pragma unroll
    for (int r = 0; r < 8; r++) s += red[c][r][ww];
    s *= (1.0f / 64.0f);
    s = (s >= 0.f) ? s : 0.01f * s;
    actg[(((size_t)b * CDIM + cg * 8 + c) * WN + wh) * WN + ww] = s;
}

// ---------- kernel 1a2: off/sc matvec. grid = B*WN, block = 256 ----------
__global__ __launch_bounds__(256) void k_offmv(const float* __restrict__ actg,
                                               const float* __restrict__ off_w,
                                               const float* __restrict__ off_b,
                                               const float* __restrict__ sc_w,
                                               const float* __restrict__ sc_b,
                                               float* __restrict__ offsc) {
    __shared__ float act[CDIM][WN + 1];
    int b = blockIdx.x >> 5, wh = blockIdx.x & 31;
    int t = threadIdx.x;
    for (int i = t; i < CDIM * WN; i += 256) {
        int c = i >> 5, ww = i & 31;
        act[c][ww] = actg[(((size_t)b * CDIM + c) * WN + wh) * WN + ww];
    }
    __syncthreads();
    int ww = t >> 3, oi = t & 7;
    float ao = off_b[oi], as = sc_b[oi];
    #pragma unroll 8
    for (int c = 0; c < CDIM; c++) {
        float av = act[c][ww];
        ao += av * off_w[oi * CDIM + c];
        as += av * sc_w[oi * CDIM + c];
    }
    ao *= (1.0f / 32.0f);
    int n = oi >> 1, d = oi & 1;
    size_t base = (((size_t)(b * NHEADS + n) * NWIN) + wh * WN + ww) << 2;
    offsc[base + d] = ao;
    offsc[base + 2 + d] = as;
}

// ---------- kernel 2: Q/K/V projection via MFMA, f16 maps (b,n,y,x,16) ----------
__global__ __launch_bounds__(256) void k_qkv_mfma(const float* __restrict__ x,
                                                  const u16* __restrict__ wbf,
                                                  const float* __restrict__ qkv_b,
                                                  u16* __restrict__ qm,
                                                  u16* __restrict__ km,
                                                  u16* __restrict__ vm) {
    __shared__ u16 Alds[256 * 64];   // [px][c] f16 bits, chunk-of-8 XOR-swizzled

    int bid = blockIdx.x;
    bid = (bid & 7) * 256 + (bid >> 3);   // XCD swizzle (2048 % 8 == 0, bijective)
    int b = bid >> 8, y = bid & 255;
    int t = threadIdx.x;

    {
        const float* xp = x + ((size_t)b * CDIM * IMG + y) * IMG + t;
        u16* row = Alds + t * 64;
        int sw = t & 7;
        #pragma unroll
        for (int cp = 0; cp < 32; cp++) {
            float a = xp[(size_t)(2 * cp) * IMG * IMG];
            float bq = xp[(size_t)(2 * cp + 1) * IMG * IMG];
            unsigned pk = cvt_pk_f16(a, bq);
            int c = 2 * cp;
            int chunk = c >> 3;
            *(unsigned*)(row + ((chunk ^ sw) << 3) + (c & 7)) = pk;
        }
    }
    // no barrier: wave wv only reads rows [wv*64, wv*64+64) written by its own lanes

    int wv = t >> 6, l = t & 63;
    int lr = l & 15, lg = l >> 4;

    h8 afr[4][2];
    #pragma unroll
    for (int pg = 0; pg < 4; pg++) {
        int p = wv * 64 + pg * 16 + lr;
        const u16* prow = Alds + p * 64;
        int psw = p & 7;
        #pragma unroll
        for (int kb = 0; kb < 2; kb++) {
            int chunk = kb * 4 + lg;
            afr[pg][kb] = *(const h8*)(prow + ((chunk ^ psw) << 3));
        }
    }

    u16* const maps[3] = { qm, km, vm };
    #pragma unroll
    for (int ot = 0; ot < 12; ot++) {
        int o = ot * 16 + lr;
        float4 b4 = *(const float4*)(qkv_b + ot * 16 + lg * 4);
        h8 bfr0 = *(const h8*)(wbf + o * 64 + lg * 8);
        h8 bfr1 = *(const h8*)(wbf + o * 64 + 32 + lg * 8);

        f32x4 acc[4];
        #pragma unroll
        for (int pg = 0; pg < 4; pg++) {
            acc[pg] = (f32x4){ b4.x, b4.y, b4.z, b4.w };
            acc[pg] = __builtin_amdgcn_mfma_f32_16x16x32_f16(bfr0, afr[pg][0], acc[pg], 0, 0, 0);
            acc[pg] = __builtin_amdgcn_mfma_f32_16x16x32_f16(bfr1, afr[pg][1], acc[pg], 0, 0, 0);
        }

        u16* mp = maps[ot >> 2];
        int n = ot & 3;
        size_t base = ((size_t)(b * NHEADS + n) * IMG * IMG + (size_t)y * IMG) * HD;
        #pragma unroll
        for (int pg = 0; pg < 4; pg++) {
            size_t sb = base + (size_t)(wv * 64 + pg * 16 + lr) * HD + lg * 4;
            *(uint2*)(mp + sb) = make_uint2(pk_rne(acc[pg][0], acc[pg][1]),
                                            pk_rne(acc[pg][2], acc[pg][3]));
        }
    }
}

// ---------- kernel 3: deformable gather + MFMA attention + MFMA proj ----------
// grid = 8192 (b,wh,ww), block = 256; wave n = head n; lane = sample point / fragment lane
// Round-8 base; SOLE change: QK^T bias from precomputed lane-indexed global table biasT
// (one coalesced dwordx4 per (qt,kt), L2-resident) -> biasS LDS, its fill, its index math,
// and barrier 1 all removed. Waves fully decoupled until the Ob exchange.
__global__ __launch_bounds__(256, 2) void k_attn3(const u16* __restrict__ qm,
                                                  const u16* __restrict__ km,
                                                  const u16* __restrict__ vm,
                                                  const u16* __restrict__ wproj,
                                                  const float* __restrict__ proj_b,
                                                  const float* __restrict__ biasT,
                                                  const float* __restrict__ offsc,
                                                  float* __restrict__ out) {
    __shared__ _Float16 hb[NHEADS][2048];        // per head: [0,1024): K[64][16] then P[16][64]; [1024,2048): V'[16][64]
    _Float16* Ob = &hb[0][0];                    // O f16 [q][ch] (4096) ALIASES hb[0..1]; valid after barrier A

    int blk = blockIdx.x;
    blk = (blk & 7) * 1024 + (blk >> 3);         // XCD swizzle (8192 % 8 == 0, bijective)
    int b = blk >> 10, wh = (blk >> 5) & 31, ww = blk & 31;
    int tid = threadIdx.x, n = tid >> 6, l = tid & 63;
    int g = l >> 4, cl = l & 15;
    int y0 = wh * WSZ, x0 = ww * WSZ;
    const h8 z8 = {};

    // per-lane bias table base (L2-resident after first blocks)
    const float4* bT = (const float4*)biasT + n * 1024 + l;

    // per-lane offsc load (wave-uniform address -> broadcast)
    float4 os4 = *(const float4*)(offsc + ((((size_t)(b * NHEADS + n) * NWIN) + wh * WN + ww) << 2));

    // Q A-fragments straight from global f16 map (row = cl, k-half = g; g>=2 are zero pad)
    h8 qfr[4];
    {
        const u16* qb = qm + ((size_t)(b * NHEADS + n) << 16) * HD;
        #pragma unroll
        for (int qt = 0; qt < 4; qt++) {
            int q = qt * 16 + cl;
            qfr[qt] = (g < 2)
                ? *(const h8*)(qb + ((size_t)(y0 + (q >> 3)) * IMG + (x0 + (q & 7))) * HD + g * 8)
                : z8;
        }
    }

    // hoisted proj weights + bias (read-only global; latency hidden under gather/attention)
    h8 wfr[2];
    #pragma unroll
    for (int h = 0; h < 2; h++)
        wfr[h] = *(const h8*)(wproj + (n * 16 + cl) * 64 + h * 32 + g * 8);
    float4 pb4 = *(const float4*)(proj_b + n * 16 + g * 4);

    // ---- deformable bilinear gather (lane = its sample point), branchless taps ----
    {
        float offx = os4.x, offy = os4.y;
        float scx = os4.z, scy = os4.w;
        int pi = l >> 3, pj = l & 7;
        float gx = (float)(x0 + pj) + ((float)(2 * pj - 7) * (1.0f / 255.0f) * scx + offx) * 127.5f;
        float gy = (float)(y0 + pi) + ((float)(2 * pi - 7) * (1.0f / 255.0f) * scy + offy) * 127.5f;

        float fx0 = floorf(gx), fy0 = floorf(gy);
        int ix0 = (int)fx0, iy0 = (int)fy0;
        float wx1 = gx - fx0, wx0 = 1.f - wx1;
        float wy1 = gy - fy0, wy0 = 1.f - wy1;

        const u16* kb = km + ((size_t)(b * NHEADS + n) << 16) * HD;
        const u16* vb = vm + ((size_t)(b * NHEADS + n) << 16) * HD;

        int iys[2] = { iy0, iy0 + 1 };
        int ixs[2] = { ix0, ix0 + 1 };
        float wys[2] = { wy0, wy1 };
        float wxs[2] = { wx0, wx1 };

        size_t offs[4];
        h2 w2[4];
        #pragma unroll
        for (int t = 0; t < 4; t++) {
            int yy = iys[t >> 1], xq = ixs[t & 1];
            float wgt = wys[t >> 1] * wxs[t & 1];
            if (yy < 0 || yy >= IMG || xq < 0 || xq >= IMG) wgt = 0.f;   // zero-pad semantics
            int yc = min(max(yy, 0), IMG - 1), xc = min(max(xq, 0), IMG - 1);
            offs[t] = ((size_t)yc * IMG + xc) * HD;
            _Float16 hw = (_Float16)wgt;
            w2[t] = (h2){ hw, hw };
        }

        h2 kacc[8], vacc[8];
        #pragma unroll
        for (int i = 0; i < 8; i++) {
            kacc[i] = (h2){ (_Float16)0, (_Float16)0 };
            vacc[i] = (h2){ (_Float16)0, (_Float16)0 };
        }

        // K phase: issue all 8 loads, then packed-fma accumulate
        {
            uint4 t0[4], t1[4];
            #pragma unroll
            for (int t = 0; t < 4; t++) {
                const uint4* p = (const uint4*)(kb + offs[t]);
                t0[t] = p[0]; t1[t] = p[1];
            }
            #pragma unroll
            for (int t = 0; t < 4; t++) {
                kacc[0] += w2[t] * u2h2(t0[t].x); kacc[1] += w2[t] * u2h2(t0[t].y);
                kacc[2] += w2[t] * u2h2(t0[t].z); kacc[3] += w2[t] * u2h2(t0[t].w);
                kacc[4] += w2[t] * u2h2(t1[t].x); kacc[5] += w2[t] * u2h2(t1[t].y);
                kacc[6] += w2[t] * u2h2(t1[t].z); kacc[7] += w2[t] * u2h2(t1[t].w);
            }
        }
        // V phase
        {
            uint4 t0[4], t1[4];
            #pragma unroll
            for (int t = 0; t < 4; t++) {
                const uint4* p = (const uint4*)(vb + offs[t]);
                t0[t] = p[0]; t1[t] = p[1];
            }
            #pragma unroll
            for (int t = 0; t < 4; t++) {
                vacc[0] += w2[t] * u2h2(t0[t].x); vacc[1] += w2[t] * u2h2(t0[t].y);
                vacc[2] += w2[t] * u2h2(t0[t].z); vacc[3] += w2[t] * u2h2(t0[t].w);
                vacc[4] += w2[t] * u2h2(t1[t].x); vacc[5] += w2[t] * u2h2(t1[t].y);
                vacc[6] += w2[t] * u2h2(t1[t].z); vacc[7] += w2[t] * u2h2(t1[t].w);
            }
        }

        // K -> LDS [k-px][16] f16 (2 x b128)
        uint4* kp = (uint4*)(&hb[n][0] + (size_t)l * 16);
        kp[0] = make_uint4(h22u(kacc[0]), h22u(kacc[1]), h22u(kacc[2]), h22u(kacc[3]));
        kp[1] = make_uint4(h22u(kacc[4]), h22u(kacc[5]), h22u(kacc[6]), h22u(kacc[7]));

        // V' -> LDS [d][k-lin] f16, k-lin p = cl*4 + g, swizzle ^((d&3)<<4)
        int p = cl * 4 + g;
        #pragma unroll
        for (int i = 0; i < 8; i++) {
            int d0 = 2 * i, d1 = 2 * i + 1;
            hb[n][1024 + d0 * 64 + (p ^ ((d0 & 3) << 4))] = vacc[i][0];
            hb[n][1024 + d1 * 64 + (p ^ ((d1 & 3) << 4))] = vacc[i][1];
        }
    }

    // K/V fragments (same-wave DS ordering; no barrier needed)
    h8 kfr[4], vfr[2];
    #pragma unroll
    for (int kt = 0; kt < 4; kt++)
        kfr[kt] = (g < 2) ? *(const h8*)(&hb[n][0] + (kt * 16 + cl) * 16 + g * 8) : z8;
    #pragma unroll
    for (int h = 0; h < 2; h++)
        vfr[h] = *(const h8*)(&hb[n][1024] + cl * 64 + ((h * 32 + g * 8) ^ ((cl & 3) << 4)));

    // (no barrier: waves fully decoupled through gather + attention)

    // ---- QK^T with bias from the precomputed lane-indexed table ----
    f32x4 dacc[4][4];
    #pragma unroll
    for (int qt = 0; qt < 4; qt++) {
        #pragma unroll
        for (int kt = 0; kt < 4; kt++) {
            float4 cb = bT[(qt * 4 + kt) * 64];
            f32x4 c = { cb.x, cb.y, cb.z, cb.w };
            dacc[qt][kt] = __builtin_amdgcn_mfma_f32_16x16x32_f16(qfr[qt], kfr[kt], c, 0, 0, 0);
        }
    }

    // ---- softmax (no max pass: |dots*SCALE| << 1, exp2 cannot overflow) + PV ----
    _Float16* Pb = &hb[n][0];   // [16][64] f16, k-slot ^((row&3)<<4)
    f32x4 oacc[4];
    float inv_[4][4];
    #pragma unroll
    for (int qt = 0; qt < 4; qt++) {
        #pragma unroll
        for (int kt = 0; kt < 4; kt++)
            #pragma unroll
            for (int r = 0; r < 4; r++)
                dacc[qt][kt][r] = exp2f(dacc[qt][kt][r] * 0.36067376f);  // SCALE*log2(e)
        // 16-lane row sum via DPP rotate-adds (VALU-only)
        #pragma unroll
        for (int r = 0; r < 4; r++) {
            float s0 = (dacc[qt][0][r] + dacc[qt][1][r]) + (dacc[qt][2][r] + dacc[qt][3][r]);
            DPP_RADD(s0, 0x121);   // row_ror:1
            DPP_RADD(s0, 0x122);   // row_ror:2
            DPP_RADD(s0, 0x124);   // row_ror:4
            DPP_RADD(s0, 0x128);   // row_ror:8
            inv_[qt][r] = rcpf(s0);
        }
        // write P tile: row = g*4+r, k-lin = cl*4+kt (b64), swizzle ^((r&3)<<4)
        #pragma unroll
        for (int r = 0; r < 4; r++) {
            unsigned lo = cvt_pk_f16(dacc[qt][0][r], dacc[qt][1][r]);
            unsigned hi = cvt_pk_f16(dacc[qt][2][r], dacc[qt][3][r]);
            *(uint2*)((u16*)Pb + (g * 4 + r) * 64 + ((cl * 4) ^ (r << 4))) = make_uint2(lo, hi);
        }
        // PV: A-frag row = cl, k-lin = h*32+g*8+j
        f32x4 pv = { 0.f, 0.f, 0.f, 0.f };
        #pragma unroll
        for (int h = 0; h < 2; h++) {
            h8 af = *(const h8*)(Pb + cl * 64 + ((h * 32 + g * 8) ^ ((cl & 3) << 4)));
            pv = __builtin_amdgcn_mfma_f32_16x16x32_f16(af, vfr[h], pv, 0, 0, 0);
        }
        oacc[qt] = pv;
    }

    __syncthreads();   // barrier A: all waves done with hb -> Ob may overwrite hb[0..1]

    // ---- O (normalized) -> LDS f16 ----
    #pragma unroll
    for (int qt = 0; qt < 4; qt++)
        #pragma unroll
        for (int r = 0; r < 4; r++) {
            int q = qt * 16 + g * 4 + r;
            Ob[q * 64 + ((n * 16 + cl) ^ (g << 4))] = (_Float16)(oacc[qt][r] * inv_[qt][r]);
        }
    __syncthreads();   // barrier B: Ob ready

    // ---- proj via MFMA (swapped operands: D[och][q] -> coalesced 32B-run stores) ----
    #pragma unroll
    for (int qt = 0; qt < 4; qt++) {
        f32x4 pa = { pb4.x, pb4.y, pb4.z, pb4.w };
        #pragma unroll
        for (int h = 0; h < 2; h++) {
            h8 of = *(const h8*)(Ob + (qt * 16 + cl) * 64 + ((h * 32 + g * 8) ^ ((cl >> 2) << 4)));
            pa = __builtin_amdgcn_mfma_f32_16x16x32_f16(wfr[h], of, pa, 0, 0, 0);
        }
        int q = qt * 16 + cl;   // col = cl
        #pragma unroll
        for (int r = 0; r < 4; r++) {
            out[((size_t)(b * CDIM + n * 16 + g * 4 + r) * IMG + y0 + (q >> 3)) * IMG + x0 + (q & 7)] = pa[r];
        }
    }
}

// ---------- launcher ----------
extern "C" void kernel_launch(void* const* d_in, const int* in_sizes, int n_in,
                              void* d_out, int out_size, void* d_ws, size_t ws_size,
                              hipStream_t stream) {
    const float* x      = (const float*)d_in[0];
    const float* qkv_w  = (const float*)d_in[1];
    const float* qkv_b  = (const float*)d_in[2];
    const float* proj_w = (const float*)d_in[3];
    const float* proj_b = (const float*)d_in[4];
    const float* off_w  = (const float*)d_in[5];
    const float* off_b  = (const float*)d_in[6];
    const float* sc_w   = (const float*)d_in[7];
    const float* sc_b   = (const float*)d_in[8];
    const float* rel_b  = (const float*)d_in[9];
    float* out = (float*)d_out;

    float* ws = (float*)d_ws;
    float* offsc = ws;
    u16* wqkv = (u16*)(ws + OFFSC_FLOATS);   // 12288 f16
    u16* wprj = wqkv + 12288;                // 4096 f16
    float* biasT = (float*)(wprj + 4096);    // 16384 f32 (64 KB), 16B-aligned
    u16* qmm = (u16*)(biasT + BIAST_FLOATS);
    u16* kmm = qmm + MAP_ELEMS;
    u16* vmm = kmm + MAP_ELEMS;
    // actg (2 MB f32) aliases the qm map region: consumed by k_offmv BEFORE k_qkv_mfma writes qm
    float* actg = (float*)qmm;

    k_pool<<<BATCH * WN * 8, 256, 0, stream>>>(x, actg, qkv_w, proj_w, (unsigned*)wqkv,
                                               rel_b, biasT);
    k_offmv<<<BATCH * WN, 256, 0, stream>>>(actg, off_w, off_b, sc_w, sc_b, offsc);
    k_qkv_mfma<<<BATCH * IMG, 256, 0, stream>>>(x, wqkv, qkv_b, qmm, kmm, vmm);
    k_attn3<<<BATCH * NWIN, 256, 0, stream>>>(qmm, kmm, vmm, wprj, proj_b,
                                              biasT, offsc, out);
}

// Round 12
// 225.699 us; speedup vs baseline: 1.0865x; 1.0865x over previous
//
#include <hip/hip_runtime.h>

// (B, DIM, HEADS, H, W, WS, AWS) = (8, 64, 4, 256, 256, 8, 8); HD=16, no padding, SCALE=0.25
#define BATCH 8
#define CDIM 64
#define NHEADS 4
#define HD 16
#define IMG 256
#define WSZ 8
#define WN 32
#define NWIN (WN * WN)

static constexpr size_t OFFSC_FLOATS = (size_t)BATCH * NHEADS * NWIN * 4;     // 131072
static constexpr size_t MAP_ELEMS = (size_t)BATCH * NHEADS * IMG * IMG * HD;  // 33,554,432 per map

typedef unsigned short u16;
typedef __attribute__((ext_vector_type(2))) _Float16 h2;
typedef __attribute__((ext_vector_type(8))) _Float16 h8;
typedef __attribute__((ext_vector_type(4))) float f32x4;

#define QSCALE 0.36067376f   // SCALE * log2(e)
#define L2E    1.4426950f    // log2(e)

// ---------- helpers ----------
__device__ __forceinline__ unsigned cvt_pk_f16(float a, float b) {  // lo=h(a), hi=h(b), RTZ
    unsigned r;
    asm("v_cvt_pkrtz_f16_f32 %0, %1, %2" : "=v"(r) : "v"(a), "v"(b));
    return r;
}
__device__ __forceinline__ float rcpf(float s) {
    float r;
    asm("v_rcp_f32 %0, %1" : "=v"(r) : "v"(s));
    return r;
}
union UH2 { unsigned u; h2 h; };
__device__ __forceinline__ h2 u2h2(unsigned u) { UH2 x; x.u = u; return x.h; }
__device__ __forceinline__ unsigned h22u(h2 h) { UH2 x; x.h = h; return x.u; }
__device__ __forceinline__ u16 f2h(float f) {   // RNE
    _Float16 h = (_Float16)f;
    u16 r;
    __builtin_memcpy(&r, &h, 2);
    return r;
}
__device__ __forceinline__ unsigned pk_rne(float a, float b) {  // RNE packed
    return (unsigned)f2h(a) | ((unsigned)f2h(b) << 16);
}

// DPP rotate-add within 16-lane row (VALU-only, no LDS): x += rotated(x)
#define DPP_RADD(x, ctrl)                                                         \
    x += __int_as_float(__builtin_amdgcn_update_dpp(                              \
        0, __float_as_int(x), (ctrl), 0xF, 0xF, false))

// ---------- kernel 1a: pool -> leaky (+ blocks 0..31: weight fp32->f16 conversion) ----------
__global__ __launch_bounds__(256) void k_pool(const float* __restrict__ x,
                                              float* __restrict__ actg,
                                              const float* __restrict__ qkv_w,
                                              const float* __restrict__ proj_w,
                                              unsigned* __restrict__ wbf) {
    __shared__ float red[8][8][33];   // [c][row][ww]
    int bid = blockIdx.x;
    int cg = bid & 7, wh = (bid >> 3) & 31, b = bid >> 8;
    int t = threadIdx.x;
    int row = t >> 5, colg = t & 31;

    if (bid < 32) {
        int i = bid * 256 + t;   // dword-pair index
        if (i < 6144) {
            wbf[i] = cvt_pk_f16(qkv_w[2 * i], qkv_w[2 * i + 1]);
        } else {
            int j = i - 6144;
            wbf[i] = cvt_pk_f16(proj_w[2 * j], proj_w[2 * j + 1]);
        }
    }

    const float* xb = x + (((size_t)(b * CDIM + cg * 8) * IMG) + (size_t)(wh * WSZ + row)) * IMG + colg * 8;
    #pragma unroll
    for (int c = 0; c < 8; c++) {
        const float4* p4 = (const float4*)(xb + (size_t)c * IMG * IMG);
        float4 a = p4[0], bq = p4[1];
        red[c][row][colg] = a.x + a.y + a.z + a.w + bq.x + bq.y + bq.z + bq.w;
    }
    __syncthreads();
    int c = t >> 5, ww = t & 31;
    float s = 0.f;
    #pragma unroll
    for (int r = 0; r < 8; r++) s += red[c][r][ww];
    s *= (1.0f / 64.0f);
    s = (s >= 0.f) ? s : 0.01f * s;
    actg[(((size_t)b * CDIM + cg * 8 + c) * WN + wh) * WN + ww] = s;
}

// ---------- kernel 1a2: off/sc matvec. grid = B*WN, block = 256 ----------
__global__ __launch_bounds__(256) void k_offmv(const float* __restrict__ actg,
                                               const float* __restrict__ off_w,
                                               const float* __restrict__ off_b,
                                               const float* __restrict__ sc_w,
                                               const float* __restrict__ sc_b,
                                               float* __restrict__ offsc) {
    __shared__ float act[CDIM][WN + 1];
    int b = blockIdx.x >> 5, wh = blockIdx.x & 31;
    int t = threadIdx.x;
    for (int i = t; i < CDIM * WN; i += 256) {
        int c = i >> 5, ww = i & 31;
        act[c][ww] = actg[(((size_t)b * CDIM + c) * WN + wh) * WN + ww];
    }
    __syncthreads();
    int ww = t >> 3, oi = t & 7;
    float ao = off_b[oi], as = sc_b[oi];
    #pragma unroll 8
    for (int c = 0; c < CDIM; c++) {
        float av = act[c][ww];
        ao += av * off_w[oi * CDIM + c];
        as += av * sc_w[oi * CDIM + c];
    }
    ao *= (1.0f / 32.0f);
    int n = oi >> 1, d = oi & 1;
    size_t base = (((size_t)(b * NHEADS + n) * NWIN) + wh * WN + ww) << 2;
    offsc[base + d] = ao;
    offsc[base + 2 + d] = as;
}

// ---------- kernel 2: Q/K/V projection via MFMA, f16 maps (b,n,y,x,16) ----------
// Q map values are pre-scaled by QSCALE = SCALE*log2(e), so attention's exp2 needs no multiply.
__global__ __launch_bounds__(256) void k_qkv_mfma(const float* __restrict__ x,
                                                  const u16* __restrict__ wbf,
                                                  const float* __restrict__ qkv_b,
                                                  u16* __restrict__ qm,
                                                  u16* __restrict__ km,
                                                  u16* __restrict__ vm) {
    __shared__ u16 Alds[256 * 64];   // [px][c] f16 bits, chunk-of-8 XOR-swizzled

    int bid = blockIdx.x;
    bid = (bid & 7) * 256 + (bid >> 3);   // XCD swizzle (2048 % 8 == 0, bijective)
    int b = bid >> 8, y = bid & 255;
    int t = threadIdx.x;

    {
        const float* xp = x + ((size_t)b * CDIM * IMG + y) * IMG + t;
        u16* row = Alds + t * 64;
        int sw = t & 7;
        #pragma unroll
        for (int cp = 0; cp < 32; cp++) {
            float a = xp[(size_t)(2 * cp) * IMG * IMG];
            float bq = xp[(size_t)(2 * cp + 1) * IMG * IMG];
            unsigned pk = cvt_pk_f16(a, bq);
            int c = 2 * cp;
            int chunk = c >> 3;
            *(unsigned*)(row + ((chunk ^ sw) << 3) + (c & 7)) = pk;
        }
    }
    // no barrier: wave wv only reads rows [wv*64, wv*64+64) written by its own lanes

    int wv = t >> 6, l = t & 63;
    int lr = l & 15, lg = l >> 4;

    h8 afr[4][2];
    #pragma unroll
    for (int pg = 0; pg < 4; pg++) {
        int p = wv * 64 + pg * 16 + lr;
        const u16* prow = Alds + p * 64;
        int psw = p & 7;
        #pragma unroll
        for (int kb = 0; kb < 2; kb++) {
            int chunk = kb * 4 + lg;
            afr[pg][kb] = *(const h8*)(prow + ((chunk ^ psw) << 3));
        }
    }

    u16* const maps[3] = { qm, km, vm };
    #pragma unroll
    for (int ot = 0; ot < 12; ot++) {
        int o = ot * 16 + lr;
        float4 b4 = *(const float4*)(qkv_b + ot * 16 + lg * 4);
        h8 bfr0 = *(const h8*)(wbf + o * 64 + lg * 8);
        h8 bfr1 = *(const h8*)(wbf + o * 64 + 32 + lg * 8);

        f32x4 acc[4];
        #pragma unroll
        for (int pg = 0; pg < 4; pg++) {
            acc[pg] = (f32x4){ b4.x, b4.y, b4.z, b4.w };
            acc[pg] = __builtin_amdgcn_mfma_f32_16x16x32_f16(bfr0, afr[pg][0], acc[pg], 0, 0, 0);
            acc[pg] = __builtin_amdgcn_mfma_f32_16x16x32_f16(bfr1, afr[pg][1], acc[pg], 0, 0, 0);
        }

        u16* mp = maps[ot >> 2];
        int n = ot & 3;
        size_t base = ((size_t)(b * NHEADS + n) * IMG * IMG + (size_t)y * IMG) * HD;
        #pragma unroll
        for (int pg = 0; pg < 4; pg++) {
            size_t sb = base + (size_t)(wv * 64 + pg * 16 + lr) * HD + lg * 4;
            if (ot < 4) {   // Q map: fold softmax scale (after bias add, before f16 pack)
                *(uint2*)(mp + sb) = make_uint2(
                    pk_rne(acc[pg][0] * QSCALE, acc[pg][1] * QSCALE),
                    pk_rne(acc[pg][2] * QSCALE, acc[pg][3] * QSCALE));
            } else {
                *(uint2*)(mp + sb) = make_uint2(pk_rne(acc[pg][0], acc[pg][1]),
                                                pk_rne(acc[pg][2], acc[pg][3]));
            }
        }
    }
}

// ---------- kernel 3: deformable gather + MFMA attention + MFMA proj ----------
// grid = 8192 (b,wh,ww), block = 256; wave n = head n; lane = sample point / fragment lane
// Round-8 base; Q map pre-scaled by QSCALE -> bias acc-init uses log2(e), exp2 takes dacc directly.
__global__ __launch_bounds__(256, 2) void k_attn3(const u16* __restrict__ qm,
                                                  const u16* __restrict__ km,
                                                  const u16* __restrict__ vm,
                                                  const u16* __restrict__ wproj,
                                                  const float* __restrict__ proj_b,
                                                  const float* __restrict__ rel_bias,
                                                  const float* __restrict__ offsc,
                                                  float* __restrict__ out) {
    __shared__ float biasS[NHEADS * 225];        // [head][225], pre-scaled by log2(e)
    __shared__ _Float16 hb[NHEADS][2048];        // per head: [0,1024): K[64][16] then P[16][64]; [1024,2048): V'[16][64]
    _Float16* Ob = &hb[0][0];                    // O f16 [q][ch] (4096) ALIASES hb[0..1]; valid after barrier 2

    int blk = blockIdx.x;
    blk = (blk & 7) * 1024 + (blk >> 3);         // XCD swizzle (8192 % 8 == 0, bijective)
    int b = blk >> 10, wh = (blk >> 5) & 31, ww = blk & 31;
    int tid = threadIdx.x, n = tid >> 6, l = tid & 63;
    int g = l >> 4, cl = l & 15;
    int y0 = wh * WSZ, x0 = ww * WSZ;
    const h8 z8 = {};

    for (int i = tid; i < NHEADS * 225; i += 256) {
        int hn = i / 225, idx = i - hn * 225;
        biasS[i] = rel_bias[idx * NHEADS + hn] * L2E;
    }

    // per-lane offsc load (wave-uniform address -> broadcast)
    float4 os4 = *(const float4*)(offsc + ((((size_t)(b * NHEADS + n) * NWIN) + wh * WN + ww) << 2));

    // Q A-fragments straight from global f16 map (row = cl, k-half = g; g>=2 are zero pad)
    h8 qfr[4];
    {
        const u16* qb = qm + ((size_t)(b * NHEADS + n) << 16) * HD;
        #pragma unroll
        for (int qt = 0; qt < 4; qt++) {
            int q = qt * 16 + cl;
            qfr[qt] = (g < 2)
                ? *(const h8*)(qb + ((size_t)(y0 + (q >> 3)) * IMG + (x0 + (q & 7))) * HD + g * 8)
                : z8;
        }
    }

    // hoisted proj weights + bias (read-only global; latency hidden under gather/attention)
    h8 wfr[2];
    #pragma unroll
    for (int h = 0; h < 2; h++)
        wfr[h] = *(const h8*)(wproj + (n * 16 + cl) * 64 + h * 32 + g * 8);
    float4 pb4 = *(const float4*)(proj_b + n * 16 + g * 4);

    // ---- deformable bilinear gather (lane = its sample point), branchless taps ----
    {
        float offx = os4.x, offy = os4.y;
        float scx = os4.z, scy = os4.w;
        int pi = l >> 3, pj = l & 7;
        float gx = (float)(x0 + pj) + ((float)(2 * pj - 7) * (1.0f / 255.0f) * scx + offx) * 127.5f;
        float gy = (float)(y0 + pi) + ((float)(2 * pi - 7) * (1.0f / 255.0f) * scy + offy) * 127.5f;

        float fx0 = floorf(gx), fy0 = floorf(gy);
        int ix0 = (int)fx0, iy0 = (int)fy0;
        float wx1 = gx - fx0, wx0 = 1.f - wx1;
        float wy1 = gy - fy0, wy0 = 1.f - wy1;

        const u16* kb = km + ((size_t)(b * NHEADS + n) << 16) * HD;
        const u16* vb = vm + ((size_t)(b * NHEADS + n) << 16) * HD;

        int iys[2] = { iy0, iy0 + 1 };
        int ixs[2] = { ix0, ix0 + 1 };
        float wys[2] = { wy0, wy1 };
        float wxs[2] = { wx0, wx1 };

        size_t offs[4];
        h2 w2[4];
        #pragma unroll
        for (int t = 0; t < 4; t++) {
            int yy = iys[t >> 1], xq = ixs[t & 1];
            float wgt = wys[t >> 1] * wxs[t & 1];
            if (yy < 0 || yy >= IMG || xq < 0 || xq >= IMG) wgt = 0.f;   // zero-pad semantics
            int yc = min(max(yy, 0), IMG - 1), xc = min(max(xq, 0), IMG - 1);
            offs[t] = ((size_t)yc * IMG + xc) * HD;
            _Float16 hw = (_Float16)wgt;
            w2[t] = (h2){ hw, hw };
        }

        h2 kacc[8], vacc[8];
        #pragma unroll
        for (int i = 0; i < 8; i++) {
            kacc[i] = (h2){ (_Float16)0, (_Float16)0 };
            vacc[i] = (h2){ (_Float16)0, (_Float16)0 };
        }

        // K phase: issue all 8 loads, then packed-fma accumulate
        {
            uint4 t0[4], t1[4];
            #pragma unroll
            for (int t = 0; t < 4; t++) {
                const uint4* p = (const uint4*)(kb + offs[t]);
                t0[t] = p[0]; t1[t] = p[1];
            }
            #pragma unroll
            for (int t = 0; t < 4; t++) {
                kacc[0] += w2[t] * u2h2(t0[t].x); kacc[1] += w2[t] * u2h2(t0[t].y);
                kacc[2] += w2[t] * u2h2(t0[t].z); kacc[3] += w2[t] * u2h2(t0[t].w);
                kacc[4] += w2[t] * u2h2(t1[t].x); kacc[5] += w2[t] * u2h2(t1[t].y);
                kacc[6] += w2[t] * u2h2(t1[t].z); kacc[7] += w2[t] * u2h2(t1[t].w);
            }
        }
        // V phase
        {
            uint4 t0[4], t1[4];
            #pragma unroll
            for (int t = 0; t < 4; t++) {
                const uint4* p = (const uint4*)(vb + offs[t]);
                t0[t] = p[0]; t1[t] = p[1];
            }
            #pragma unroll
            for (int t = 0; t < 4; t++) {
                vacc[0] += w2[t] * u2h2(t0[t].x); vacc[1] += w2[t] * u2h2(t0[t].y);
                vacc[2] += w2[t] * u2h2(t0[t].z); vacc[3] += w2[t] * u2h2(t0[t].w);
                vacc[4] += w2[t] * u2h2(t1[t].x); vacc[5] += w2[t] * u2h2(t1[t].y);
                vacc[6] += w2[t] * u2h2(t1[t].z); vacc[7] += w2[t] * u2h2(t1[t].w);
            }
        }

        // K -> LDS [k-px][16] f16 (2 x b128)
        uint4* kp = (uint4*)(&hb[n][0] + (size_t)l * 16);
        kp[0] = make_uint4(h22u(kacc[0]), h22u(kacc[1]), h22u(kacc[2]), h22u(kacc[3]));
        kp[1] = make_uint4(h22u(kacc[4]), h22u(kacc[5]), h22u(kacc[6]), h22u(kacc[7]));

        // V' -> LDS [d][k-lin] f16, k-lin p = cl*4 + g, swizzle ^((d&3)<<4)
        int p = cl * 4 + g;
        #pragma unroll
        for (int i = 0; i < 8; i++) {
            int d0 = 2 * i, d1 = 2 * i + 1;
            hb[n][1024 + d0 * 64 + (p ^ ((d0 & 3) << 4))] = vacc[i][0];
            hb[n][1024 + d1 * 64 + (p ^ ((d1 & 3) << 4))] = vacc[i][1];
        }
    }

    // K/V fragments (same-wave DS ordering; no barrier needed)
    h8 kfr[4], vfr[2];
    #pragma unroll
    for (int kt = 0; kt < 4; kt++)
        kfr[kt] = (g < 2) ? *(const h8*)(&hb[n][0] + (kt * 16 + cl) * 16 + g * 8) : z8;
    #pragma unroll
    for (int h = 0; h < 2; h++)
        vfr[h] = *(const h8*)(&hb[n][1024] + cl * 64 + ((h * 32 + g * 8) ^ ((cl & 3) << 4)));

    __syncthreads();   // barrier 1: biasS ready

    // ---- QK^T with bias folded into acc init (Q pre-scaled; biasS pre-scaled by log2e) ----
    f32x4 dacc[4][4];
    #pragma unroll
    for (int qt = 0; qt < 4; qt++) {
        #pragma unroll
        for (int kt = 0; kt < 4; kt++) {
            int pik = kt * 2 + (cl >> 3), pjk = cl & 7;
            int bidx = n * 225 + (7 - pik) * 15 + (7 - pjk) + (qt * 2 + (g >> 1)) * 15 + (g & 1) * 4;
            f32x4 c = { biasS[bidx], biasS[bidx + 1], biasS[bidx + 2], biasS[bidx + 3] };
            dacc[qt][kt] = __builtin_amdgcn_mfma_f32_16x16x32_f16(qfr[qt], kfr[kt], c, 0, 0, 0);
        }
    }

    // ---- softmax (no max pass; exp2 argument already scaled) + PV ----
    _Float16* Pb = &hb[n][0];   // [16][64] f16, k-slot ^((row&3)<<4)
    f32x4 oacc[4];
    float inv_[4][4];
    #pragma unroll
    for (int qt = 0; qt < 4; qt++) {
        #pragma unroll
        for (int kt = 0; kt < 4; kt++)
            #pragma unroll
            for (int r = 0; r < 4; r++)
                dacc[qt][kt][r] = exp2f(dacc[qt][kt][r]);
        // 16-lane row sum via DPP rotate-adds (VALU-only)
        #pragma unroll
        for (int r = 0; r < 4; r++) {
            float s0 = (dacc[qt][0][r] + dacc[qt][1][r]) + (dacc[qt][2][r] + dacc[qt][3][r]);
            DPP_RADD(s0, 0x121);   // row_ror:1
            DPP_RADD(s0, 0x122);   // row_ror:2
            DPP_RADD(s0, 0x124);   // row_ror:4
            DPP_RADD(s0, 0x128);   // row_ror:8
            inv_[qt][r] = rcpf(s0);
        }
        // write P tile: row = g*4+r, k-lin = cl*4+kt (b64), swizzle ^((r&3)<<4)
        #pragma unroll
        for (int r = 0; r < 4; r++) {
            unsigned lo = cvt_pk_f16(dacc[qt][0][r], dacc[qt][1][r]);
            unsigned hi = cvt_pk_f16(dacc[qt][2][r], dacc[qt][3][r]);
            *(uint2*)((u16*)Pb + (g * 4 + r) * 64 + ((cl * 4) ^ (r << 4))) = make_uint2(lo, hi);
        }
        // PV: A-frag row = cl, k-lin = h*32+g*8+j
        f32x4 pv = { 0.f, 0.f, 0.f, 0.f };
        #pragma unroll
        for (int h = 0; h < 2; h++) {
            h8 af = *(const h8*)(Pb + cl * 64 + ((h * 32 + g * 8) ^ ((cl & 3) << 4)));
            pv = __builtin_amdgcn_mfma_f32_16x16x32_f16(af, vfr[h], pv, 0, 0, 0);
        }
        oacc[qt] = pv;
    }

    __syncthreads();   // barrier 2: all waves done with hb -> Ob may overwrite hb[0..1]

    // ---- O (normalized) -> LDS f16 ----
    #pragma unroll
    for (int qt = 0; qt < 4; qt++)
        #pragma unroll
        for (int r = 0; r < 4; r++) {
            int q = qt * 16 + g * 4 + r;
            Ob[q * 64 + ((n * 16 + cl) ^ (g << 4))] = (_Float16)(oacc[qt][r] * inv_[qt][r]);
        }
    __syncthreads();   // barrier 3: Ob ready

    // ---- proj via MFMA (swapped operands: D[och][q] -> coalesced 32B-run stores) ----
    #pragma unroll
    for (int qt = 0; qt < 4; qt++) {
        f32x4 pa = { pb4.x, pb4.y, pb4.z, pb4.w };
        #pragma unroll
        for (int h = 0; h < 2; h++) {
            h8 of = *(const h8*)(Ob + (qt * 16 + cl) * 64 + ((h * 32 + g * 8) ^ ((cl >> 2) << 4)));
            pa = __builtin_amdgcn_mfma_f32_16x16x32_f16(wfr[h], of, pa, 0, 0, 0);
        }
        int q = qt * 16 + cl;   // col = cl
        #pragma unroll
        for (int r = 0; r < 4; r++) {
            out[((size_t)(b * CDIM + n * 16 + g * 4 + r) * IMG + y0 + (q >> 3)) * IMG + x0 + (q & 7)] = pa[r];
        }
    }
}

// ---------- launcher ----------
extern "C" void kernel_launch(void* const* d_in, const int* in_sizes, int n_in,
                              void* d_out, int out_size, void* d_ws, size_t ws_size,
                              hipStream_t stream) {
    const float* x      = (const float*)d_in[0];
    const float* qkv_w  = (const float*)d_in[1];
    const float* qkv_b  = (const float*)d_in[2];
    const float* proj_w = (const float*)d_in[3];
    const float* proj_b = (const float*)d_in[4];
    const float* off_w  = (const float*)d_in[5];
    const float* off_b  = (const float*)d_in[6];
    const float* sc_w   = (const float*)d_in[7];
    const float* sc_b   = (const float*)d_in[8];
    const float* rel_b  = (const float*)d_in[9];
    float* out = (float*)d_out;

    float* ws = (float*)d_ws;
    float* offsc = ws;
    u16* wqkv = (u16*)(ws + OFFSC_FLOATS);   // 12288 f16
    u16* wprj = wqkv + 12288;                // 4096 f16
    u16* qmm = wprj + 4096;
    u16* kmm = qmm + MAP_ELEMS;
    u16* vmm = kmm + MAP_ELEMS;
    // actg (2 MB f32) aliases the qm map region: consumed by k_offmv BEFORE k_qkv_mfma writes qm
    float* actg = (float*)qmm;

    k_pool<<<BATCH * WN * 8, 256, 0, stream>>>(x, actg, qkv_w, proj_w, (unsigned*)wqkv);
    k_offmv<<<BATCH * WN, 256, 0, stream>>>(actg, off_w, off_b, sc_w, sc_b, offsc);
    k_qkv_mfma<<<BATCH * IMG, 256, 0, stream>>>(x, wqkv, qkv_b, qmm, kmm, vmm);
    k_attn3<<<BATCH * NWIN, 256, 0, stream>>>(qmm, kmm, vmm, wprj, proj_b,
                                              rel_b, offsc, out);
}

// Round 14
// 224.681 us; speedup vs baseline: 1.0915x; 1.0045x over previous
//
#include <hip/hip_runtime.h>

// (B, DIM, HEADS, H, W, WS, AWS) = (8, 64, 4, 256, 256, 8, 8); HD=16, no padding, SCALE=0.25
#define BATCH 8
#define CDIM 64
#define NHEADS 4
#define HD 16
#define IMG 256
#define WSZ 8
#define WN 32
#define NWIN (WN * WN)

static constexpr size_t OFFSC_FLOATS = (size_t)BATCH * NHEADS * NWIN * 4;     // 131072
static constexpr size_t MAP_ELEMS = (size_t)BATCH * NHEADS * IMG * IMG * HD;  // 33,554,432 per map

typedef unsigned short u16;
typedef __attribute__((ext_vector_type(2))) _Float16 h2;
typedef __attribute__((ext_vector_type(8))) _Float16 h8;
typedef __attribute__((ext_vector_type(4))) float f32x4;

#define QSCALE 0.36067376f   // SCALE * log2(e)
#define L2E    1.4426950f    // log2(e)

// ---------- helpers ----------
__device__ __forceinline__ unsigned cvt_pk_f16(float a, float b) {  // lo=h(a), hi=h(b), RTZ
    unsigned r;
    asm("v_cvt_pkrtz_f16_f32 %0, %1, %2" : "=v"(r) : "v"(a), "v"(b));
    return r;
}
__device__ __forceinline__ float rcpf(float s) {
    float r;
    asm("v_rcp_f32 %0, %1" : "=v"(r) : "v"(s));
    return r;
}
union UH2 { unsigned u; h2 h; };
__device__ __forceinline__ h2 u2h2(unsigned u) { UH2 x; x.u = u; return x.h; }
__device__ __forceinline__ unsigned h22u(h2 h) { UH2 x; x.h = h; return x.u; }
__device__ __forceinline__ u16 f2h(float f) {   // RNE
    _Float16 h = (_Float16)f;
    u16 r;
    __builtin_memcpy(&r, &h, 2);
    return r;
}
__device__ __forceinline__ unsigned pk_rne(float a, float b) {  // RNE packed
    return (unsigned)f2h(a) | ((unsigned)f2h(b) << 16);
}

// DPP rotate-add within 16-lane row (VALU-only, no LDS): x += rotated(x)
#define DPP_RADD(x, ctrl)                                                         \
    x += __int_as_float(__builtin_amdgcn_update_dpp(                              \
        0, __float_as_int(x), (ctrl), 0xF, 0xF, false))

// ---------- kernel 1a: pool -> leaky (+ blocks 0..31: weight fp32->f16 conversion) ----------
__global__ __launch_bounds__(256) void k_pool(const float* __restrict__ x,
                                              float* __restrict__ actg,
                                              const float* __restrict__ qkv_w,
                                              const float* __restrict__ proj_w,
                                              unsigned* __restrict__ wbf) {
    __shared__ float red[8][8][33];   // [c][row][ww]
    int bid = blockIdx.x;
    int cg = bid & 7, wh = (bid >> 3) & 31, b = bid >> 8;
    int t = threadIdx.x;
    int row = t >> 5, colg = t & 31;

    if (bid < 32) {
        int i = bid * 256 + t;   // dword-pair index
        if (i < 6144) {
            wbf[i] = cvt_pk_f16(qkv_w[2 * i], qkv_w[2 * i + 1]);
        } else {
            int j = i - 6144;
            wbf[i] = cvt_pk_f16(proj_w[2 * j], proj_w[2 * j + 1]);
        }
    }

    const float* xb = x + (((size_t)(b * CDIM + cg * 8) * IMG) + (size_t)(wh * WSZ + row)) * IMG + colg * 8;
    #pragma unroll
    for (int c = 0; c < 8; c++) {
        const float4* p4 = (const float4*)(xb + (size_t)c * IMG * IMG);
        float4 a = p4[0], bq = p4[1];
        red[c][row][colg] = a.x + a.y + a.z + a.w + bq.x + bq.y + bq.z + bq.w;
    }
    __syncthreads();
    int c = t >> 5, ww = t & 31;
    float s = 0.f;
    #pragma unroll
    for (int r = 0; r < 8; r++) s += red[c][r][ww];
    s *= (1.0f / 64.0f);
    s = (s >= 0.f) ? s : 0.01f * s;
    actg[(((size_t)b * CDIM + cg * 8 + c) * WN + wh) * WN + ww] = s;
}

// ---------- kernel 1a2: off/sc matvec. grid = B*WN, block = 256 ----------
__global__ __launch_bounds__(256) void k_offmv(const float* __restrict__ actg,
                                               const float* __restrict__ off_w,
                                               const float* __restrict__ off_b,
                                               const float* __restrict__ sc_w,
                                               const float* __restrict__ sc_b,
                                               float* __restrict__ offsc) {
    __shared__ float act[CDIM][WN + 1];
    int b = blockIdx.x >> 5, wh = blockIdx.x & 31;
    int t = threadIdx.x;
    for (int i = t; i < CDIM * WN; i += 256) {
        int c = i >> 5, ww = i & 31;
        act[c][ww] = actg[(((size_t)b * CDIM + c) * WN + wh) * WN + ww];
    }
    __syncthreads();
    int ww = t >> 3, oi = t & 7;
    float ao = off_b[oi], as = sc_b[oi];
    #pragma unroll 8
    for (int c = 0; c < CDIM; c++) {
        float av = act[c][ww];
        ao += av * off_w[oi * CDIM + c];
        as += av * sc_w[oi * CDIM + c];
    }
    ao *= (1.0f / 32.0f);
    int n = oi >> 1, d = oi & 1;
    size_t base = (((size_t)(b * NHEADS + n) * NWIN) + wh * WN + ww) << 2;
    offsc[base + d] = ao;
    offsc[base + 2 + d] = as;
}

// ---------- kernel 2: Q/K/V projection via MFMA, f16 maps (b,n,y,x,16) ----------
// Q map values are pre-scaled by QSCALE = SCALE*log2(e), so attention's exp2 needs no multiply.
__global__ __launch_bounds__(256) void k_qkv_mfma(const float* __restrict__ x,
                                                  const u16* __restrict__ wbf,
                                                  const float* __restrict__ qkv_b,
                                                  u16* __restrict__ qm,
                                                  u16* __restrict__ km,
                                                  u16* __restrict__ vm) {
    __shared__ u16 Alds[256 * 64];   // [px][c] f16 bits, chunk-of-8 XOR-swizzled

    int bid = blockIdx.x;
    bid = (bid & 7) * 256 + (bid >> 3);   // XCD swizzle (2048 % 8 == 0, bijective)
    int b = bid >> 8, y = bid & 255;
    int t = threadIdx.x;

    {
        const float* xp = x + ((size_t)b * CDIM * IMG + y) * IMG + t;
        u16* row = Alds + t * 64;
        int sw = t & 7;
        #pragma unroll
        for (int cp = 0; cp < 32; cp++) {
            float a = xp[(size_t)(2 * cp) * IMG * IMG];
            float bq = xp[(size_t)(2 * cp + 1) * IMG * IMG];
            unsigned pk = cvt_pk_f16(a, bq);
            int c = 2 * cp;
            int chunk = c >> 3;
            *(unsigned*)(row + ((chunk ^ sw) << 3) + (c & 7)) = pk;
        }
    }
    // no barrier: wave wv only reads rows [wv*64, wv*64+64) written by its own lanes

    int wv = t >> 6, l = t & 63;
    int lr = l & 15, lg = l >> 4;

    h8 afr[4][2];
    #pragma unroll
    for (int pg = 0; pg < 4; pg++) {
        int p = wv * 64 + pg * 16 + lr;
        const u16* prow = Alds + p * 64;
        int psw = p & 7;
        #pragma unroll
        for (int kb = 0; kb < 2; kb++) {
            int chunk = kb * 4 + lg;
            afr[pg][kb] = *(const h8*)(prow + ((chunk ^ psw) << 3));
        }
    }

    u16* const maps[3] = { qm, km, vm };
    #pragma unroll
    for (int ot = 0; ot < 12; ot++) {
        int o = ot * 16 + lr;
        float4 b4 = *(const float4*)(qkv_b + ot * 16 + lg * 4);
        h8 bfr0 = *(const h8*)(wbf + o * 64 + lg * 8);
        h8 bfr1 = *(const h8*)(wbf + o * 64 + 32 + lg * 8);

        f32x4 acc[4];
        #pragma unroll
        for (int pg = 0; pg < 4; pg++) {
            acc[pg] = (f32x4){ b4.x, b4.y, b4.z, b4.w };
            acc[pg] = __builtin_amdgcn_mfma_f32_16x16x32_f16(bfr0, afr[pg][0], acc[pg], 0, 0, 0);
            acc[pg] = __builtin_amdgcn_mfma_f32_16x16x32_f16(bfr1, afr[pg][1], acc[pg], 0, 0, 0);
        }

        u16* mp = maps[ot >> 2];
        int n = ot & 3;
        size_t base = ((size_t)(b * NHEADS + n) * IMG * IMG + (size_t)y * IMG) * HD;
        #pragma unroll
        for (int pg = 0; pg < 4; pg++) {
            size_t sb = base + (size_t)(wv * 64 + pg * 16 + lr) * HD + lg * 4;
            if (ot < 4) {   // Q map: fold softmax scale (after bias add, before f16 pack)
                *(uint2*)(mp + sb) = make_uint2(
                    pk_rne(acc[pg][0] * QSCALE, acc[pg][1] * QSCALE),
                    pk_rne(acc[pg][2] * QSCALE, acc[pg][3] * QSCALE));
            } else {
                *(uint2*)(mp + sb) = make_uint2(pk_rne(acc[pg][0], acc[pg][1]),
                                                pk_rne(acc[pg][2], acc[pg][3]));
            }
        }
    }
}

// ---------- kernel 3: deformable gather + MFMA attention + MFMA proj ----------
// grid = 8192 (b,wh,ww), block = 256; wave n = head n; lane = sample point / fragment lane
// Round-12 base; SOLE change: exp2f -> __builtin_amdgcn_exp2f (compiler-managed v_exp_f32:
// hazard nops inserted, no ocml denorm fixup; args bounded so fixup is dead weight)
__global__ __launch_bounds__(256, 2) void k_attn3(const u16* __restrict__ qm,
                                                  const u16* __restrict__ km,
                                                  const u16* __restrict__ vm,
                                                  const u16* __restrict__ wproj,
                                                  const float* __restrict__ proj_b,
                                                  const float* __restrict__ rel_bias,
                                                  const float* __restrict__ offsc,
                                                  float* __restrict__ out) {
    __shared__ float biasS[NHEADS * 225];        // [head][225], pre-scaled by log2(e)
    __shared__ _Float16 hb[NHEADS][2048];        // per head: [0,1024): K[64][16] then P[16][64]; [1024,2048): V'[16][64]
    _Float16* Ob = &hb[0][0];                    // O f16 [q][ch] (4096) ALIASES hb[0..1]; valid after barrier 2

    int blk = blockIdx.x;
    blk = (blk & 7) * 1024 + (blk >> 3);         // XCD swizzle (8192 % 8 == 0, bijective)
    int b = blk >> 10, wh = (blk >> 5) & 31, ww = blk & 31;
    int tid = threadIdx.x, n = tid >> 6, l = tid & 63;
    int g = l >> 4, cl = l & 15;
    int y0 = wh * WSZ, x0 = ww * WSZ;
    const h8 z8 = {};

    for (int i = tid; i < NHEADS * 225; i += 256) {
        int hn = i / 225, idx = i - hn * 225;
        biasS[i] = rel_bias[idx * NHEADS + hn] * L2E;
    }

    // per-lane offsc load (wave-uniform address -> broadcast)
    float4 os4 = *(const float4*)(offsc + ((((size_t)(b * NHEADS + n) * NWIN) + wh * WN + ww) << 2));

    // Q A-fragments straight from global f16 map (row = cl, k-half = g; g>=2 are zero pad)
    h8 qfr[4];
    {
        const u16* qb = qm + ((size_t)(b * NHEADS + n) << 16) * HD;
        #pragma unroll
        for (int qt = 0; qt < 4; qt++) {
            int q = qt * 16 + cl;
            qfr[qt] = (g < 2)
                ? *(const h8*)(qb + ((size_t)(y0 + (q >> 3)) * IMG + (x0 + (q & 7))) * HD + g * 8)
                : z8;
        }
    }

    // hoisted proj weights + bias (read-only global; latency hidden under gather/attention)
    h8 wfr[2];
    #pragma unroll
    for (int h = 0; h < 2; h++)
        wfr[h] = *(const h8*)(wproj + (n * 16 + cl) * 64 + h * 32 + g * 8);
    float4 pb4 = *(const float4*)(proj_b + n * 16 + g * 4);

    // ---- deformable bilinear gather (lane = its sample point), branchless taps ----
    {
        float offx = os4.x, offy = os4.y;
        float scx = os4.z, scy = os4.w;
        int pi = l >> 3, pj = l & 7;
        float gx = (float)(x0 + pj) + ((float)(2 * pj - 7) * (1.0f / 255.0f) * scx + offx) * 127.5f;
        float gy = (float)(y0 + pi) + ((float)(2 * pi - 7) * (1.0f / 255.0f) * scy + offy) * 127.5f;

        float fx0 = floorf(gx), fy0 = floorf(gy);
        int ix0 = (int)fx0, iy0 = (int)fy0;
        float wx1 = gx - fx0, wx0 = 1.f - wx1;
        float wy1 = gy - fy0, wy0 = 1.f - wy1;

        const u16* kb = km + ((size_t)(b * NHEADS + n) << 16) * HD;
        const u16* vb = vm + ((size_t)(b * NHEADS + n) << 16) * HD;

        int iys[2] = { iy0, iy0 + 1 };
        int ixs[2] = { ix0, ix0 + 1 };
        float wys[2] = { wy0, wy1 };
        float wxs[2] = { wx0, wx1 };

        size_t offs[4];
        h2 w2[4];
        #pragma unroll
        for (int t = 0; t < 4; t++) {
            int yy = iys[t >> 1], xq = ixs[t & 1];
            float wgt = wys[t >> 1] * wxs[t & 1];
            if (yy < 0 || yy >= IMG || xq < 0 || xq >= IMG) wgt = 0.f;   // zero-pad semantics
            int yc = min(max(yy, 0), IMG - 1), xc = min(max(xq, 0), IMG - 1);
            offs[t] = ((size_t)yc * IMG + xc) * HD;
            _Float16 hw = (_Float16)wgt;
            w2[t] = (h2){ hw, hw };
        }

        h2 kacc[8], vacc[8];
        #pragma unroll
        for (int i = 0; i < 8; i++) {
            kacc[i] = (h2){ (_Float16)0, (_Float16)0 };
            vacc[i] = (h2){ (_Float16)0, (_Float16)0 };
        }

        // K phase: issue all 8 loads, then packed-fma accumulate
        {
            uint4 t0[4], t1[4];
            #pragma unroll
            for (int t = 0; t < 4; t++) {
                const uint4* p = (const uint4*)(kb + offs[t]);
                t0[t] = p[0]; t1[t] = p[1];
            }
            #pragma unroll
            for (int t = 0; t < 4; t++) {
                kacc[0] += w2[t] * u2h2(t0[t].x); kacc[1] += w2[t] * u2h2(t0[t].y);
                kacc[2] += w2[t] * u2h2(t0[t].z); kacc[3] += w2[t] * u2h2(t0[t].w);
                kacc[4] += w2[t] * u2h2(t1[t].x); kacc[5] += w2[t] * u2h2(t1[t].y);
                kacc[6] += w2[t] * u2h2(t1[t].z); kacc[7] += w2[t] * u2h2(t1[t].w);
            }
        }
        // V phase
        {
            uint4 t0[4], t1[4];
            #pragma unroll
            for (int t = 0; t < 4; t++) {
                const uint4* p = (const uint4*)(vb + offs[t]);
                t0[t] = p[0]; t1[t] = p[1];
            }
            #pragma unroll
            for (int t = 0; t < 4; t++) {
                vacc[0] += w2[t] * u2h2(t0[t].x); vacc[1] += w2[t] * u2h2(t0[t].y);
                vacc[2] += w2[t] * u2h2(t0[t].z); vacc[3] += w2[t] * u2h2(t0[t].w);
                vacc[4] += w2[t] * u2h2(t1[t].x); vacc[5] += w2[t] * u2h2(t1[t].y);
                vacc[6] += w2[t] * u2h2(t1[t].z); vacc[7] += w2[t] * u2h2(t1[t].w);
            }
        }

        // K -> LDS [k-px][16] f16 (2 x b128)
        uint4* kp = (uint4*)(&hb[n][0] + (size_t)l * 16);
        kp[0] = make_uint4(h22u(kacc[0]), h22u(kacc[1]), h22u(kacc[2]), h22u(kacc[3]));
        kp[1] = make_uint4(h22u(kacc[4]), h22u(kacc[5]), h22u(kacc[6]), h22u(kacc[7]));

        // V' -> LDS [d][k-lin] f16, k-lin p = cl*4 + g, swizzle ^((d&3)<<4)
        int p = cl * 4 + g;
        #pragma unroll
        for (int i = 0; i < 8; i++) {
            int d0 = 2 * i, d1 = 2 * i + 1;
            hb[n][1024 + d0 * 64 + (p ^ ((d0 & 3) << 4))] = vacc[i][0];
            hb[n][1024 + d1 * 64 + (p ^ ((d1 & 3) << 4))] = vacc[i][1];
        }
    }

    // K/V fragments (same-wave DS ordering; no barrier needed)
    h8 kfr[4], vfr[2];
    #pragma unroll
    for (int kt = 0; kt < 4; kt++)
        kfr[kt] = (g < 2) ? *(const h8*)(&hb[n][0] + (kt * 16 + cl) * 16 + g * 8) : z8;
    #pragma unroll
    for (int h = 0; h < 2; h++)
        vfr[h] = *(const h8*)(&hb[n][1024] + cl * 64 + ((h * 32 + g * 8) ^ ((cl & 3) << 4)));

    __syncthreads();   // barrier 1: biasS ready

    // ---- QK^T with bias folded into acc init (Q pre-scaled; biasS pre-scaled by log2e) ----
    f32x4 dacc[4][4];
    #pragma unroll
    for (int qt = 0; qt < 4; qt++) {
        #pragma unroll
        for (int kt = 0; kt < 4; kt++) {
            int pik = kt * 2 + (cl >> 3), pjk = cl & 7;
            int bidx = n * 225 + (7 - pik) * 15 + (7 - pjk) + (qt * 2 + (g >> 1)) * 15 + (g & 1) * 4;
            f32x4 c = { biasS[bidx], biasS[bidx + 1], biasS[bidx + 2], biasS[bidx + 3] };
            dacc[qt][kt] = __builtin_amdgcn_mfma_f32_16x16x32_f16(qfr[qt], kfr[kt], c, 0, 0, 0);
        }
    }

    // ---- softmax (no max pass; exp2 argument already scaled; intrinsic v_exp_f32) + PV ----
    _Float16* Pb = &hb[n][0];   // [16][64] f16, k-slot ^((row&3)<<4)
    f32x4 oacc[4];
    float inv_[4][4];
    #pragma unroll
    for (int qt = 0; qt < 4; qt++) {
        #pragma unroll
        for (int kt = 0; kt < 4; kt++)
            #pragma unroll
            for (int r = 0; r < 4; r++)
                dacc[qt][kt][r] = __builtin_amdgcn_exp2f(dacc[qt][kt][r]);
        // 16-lane row sum via DPP rotate-adds (VALU-only)
        #pragma unroll
        for (int r = 0; r < 4; r++) {
            float s0 = (dacc[qt][0][r] + dacc[qt][1][r]) + (dacc[qt][2][r] + dacc[qt][3][r]);
            DPP_RADD(s0, 0x121);   // row_ror:1
            DPP_RADD(s0, 0x122);   // row_ror:2
            DPP_RADD(s0, 0x124);   // row_ror:4
            DPP_RADD(s0, 0x128);   // row_ror:8
            inv_[qt][r] = rcpf(s0);
        }
        // write P tile: row = g*4+r, k-lin = cl*4+kt (b64), swizzle ^((r&3)<<4)
        #pragma unroll
        for (int r = 0; r < 4; r++) {
            unsigned lo = cvt_pk_f16(dacc[qt][0][r], dacc[qt][1][r]);
            unsigned hi = cvt_pk_f16(dacc[qt][2][r], dacc[qt][3][r]);
            *(uint2*)((u16*)Pb + (g * 4 + r) * 64 + ((cl * 4) ^ (r << 4))) = make_uint2(lo, hi);
        }
        // PV: A-frag row = cl, k-lin = h*32+g*8+j
        f32x4 pv = { 0.f, 0.f, 0.f, 0.f };
        #pragma unroll
        for (int h = 0; h < 2; h++) {
            h8 af = *(const h8*)(Pb + cl * 64 + ((h * 32 + g * 8) ^ ((cl & 3) << 4)));
            pv = __builtin_amdgcn_mfma_f32_16x16x32_f16(af, vfr[h], pv, 0, 0, 0);
        }
        oacc[qt] = pv;
    }

    __syncthreads();   // barrier 2: all waves done with hb -> Ob may overwrite hb[0..1]

    // ---- O (normalized) -> LDS f16 ----
    #pragma unroll
    for (int qt = 0; qt < 4; qt++)
        #pragma unroll
        for (int r = 0; r < 4; r++) {
            int q = qt * 16 + g * 4 + r;
            Ob[q * 64 + ((n * 16 + cl) ^ (g << 4))] = (_Float16)(oacc[qt][r] * inv_[qt][r]);
        }
    __syncthreads();   // barrier 3: Ob ready

    // ---- proj via MFMA (swapped operands: D[och][q] -> coalesced 32B-run stores) ----
    #pragma unroll
    for (int qt = 0; qt < 4; qt++) {
        f32x4 pa = { pb4.x, pb4.y, pb4.z, pb4.w };
        #pragma unroll
        for (int h = 0; h < 2; h++) {
            h8 of = *(const h8*)(Ob + (qt * 16 + cl) * 64 + ((h * 32 + g * 8) ^ ((cl >> 2) << 4)));
            pa = __builtin_amdgcn_mfma_f32_16x16x32_f16(wfr[h], of, pa, 0, 0, 0);
        }
        int q = qt * 16 + cl;   // col = cl
        #pragma unroll
        for (int r = 0; r < 4; r++) {
            out[((size_t)(b * CDIM + n * 16 + g * 4 + r) * IMG + y0 + (q >> 3)) * IMG + x0 + (q & 7)] = pa[r];
        }
    }
}

// ---------- launcher ----------
extern "C" void kernel_launch(void* const* d_in, const int* in_sizes, int n_in,
                              void* d_out, int out_size, void* d_ws, size_t ws_size,
                              hipStream_t stream) {
    const float* x      = (const float*)d_in[0];
    const float* qkv_w  = (const float*)d_in[1];
    const float* qkv_b  = (const float*)d_in[2];
    const float* proj_w = (const float*)d_in[3];
    const float* proj_b = (const float*)d_in[4];
    const float* off_w  = (const float*)d_in[5];
    const float* off_b  = (const float*)d_in[6];
    const float* sc_w   = (const float*)d_in[7];
    const float* sc_b   = (const float*)d_in[8];
    const float* rel_b  = (const float*)d_in[9];
    float* out = (float*)d_out;

    float* ws = (float*)d_ws;
    float* offsc = ws;
    u16* wqkv = (u16*)(ws + OFFSC_FLOATS);   // 12288 f16
    u16* wprj = wqkv + 12288;                // 4096 f16
    u16* qmm = wprj + 4096;
    u16* kmm = qmm + MAP_ELEMS;
    u16* vmm = kmm + MAP_ELEMS;
    // actg (2 MB f32) aliases the qm map region: consumed by k_offmv BEFORE k_qkv_mfma writes qm
    float* actg = (float*)qmm;

    k_pool<<<BATCH * WN * 8, 256, 0, stream>>>(x, actg, qkv_w, proj_w, (unsigned*)wqkv);
    k_offmv<<<BATCH * WN, 256, 0, stream>>>(actg, off_w, off_b, sc_w, sc_b, offsc);
    k_qkv_mfma<<<BATCH * IMG, 256, 0, stream>>>(x, wqkv, qkv_b, qmm, kmm, vmm);
    k_attn3<<<BATCH * NWIN, 256, 0, stream>>>(qmm, kmm, vmm, wprj, proj_b,
                                              rel_b, offsc, out);
}